// Round 3
// baseline (226.699 us; speedup 1.0000x reference)
//
#include <hip/hip_runtime.h>
#include <hip/hip_bf16.h>

// FeedForwardQuantum: out[b,s,e] = relu( (cos(x[b,s,:16])*cos(theta)) @ W1^T + b1 ) @ W2^T + b2
// B=16 S=4096 E=512 F=64 Q=16. Inputs fp32, OUTPUT fp32 (reference is all-f32; the
// "bf16" in the harness assert label is a hardcoded string — rounds 1/2 failed because
// we wrote uint16 bf16 bits into a float32 buffer).
//
// 512 blocks x 256 threads; block owns 128 rows (8 M-iters of 16 rows); wave w owns
// output cols [w*128, w*128+128). W2 bf16 B-frags in registers for the whole block.
// MFMA lane mappings (A[m=lane&15][k=quad*8+j], B sym., C col=lane&15 row=quad*4+reg)
// were validated by the round-2 runtime probe (probe output == hardcoded mapping).

#define EMBED 512
#define FFN   64
#define NQ    16
#define ROWS  65536            // 16*4096
#define ROWS_PER_BLOCK 128
#define MITERS (ROWS_PER_BLOCK / 16)
#define NBLOCKS (ROWS / ROWS_PER_BLOCK)

typedef __attribute__((ext_vector_type(8))) short short8;   // 8 x bf16 (4 VGPR)
typedef __attribute__((ext_vector_type(4))) short short4_t; // 8 B
typedef __attribute__((ext_vector_type(4))) float floatx4;  // mfma acc

__device__ __forceinline__ short f2bf(float f) {
    union { float f; unsigned u; } v; v.f = f;
    unsigned u = v.u;
    unsigned r = (u + 0x7fffu + ((u >> 16) & 1u)) >> 16;   // RNE
    return (short)r;
}

__global__ __launch_bounds__(256, 2)
void ffq_kernel(const float* __restrict__ x,
                const float* __restrict__ theta,
                const float* __restrict__ W1,
                const float* __restrict__ b1,
                const float* __restrict__ W2,
                const float* __restrict__ b2,
                float* __restrict__ out)           // fp32 output
{
    __shared__ __align__(16) float w1_s[FFN][NQ];      // 4 KB
    __shared__ __align__(16) float z_s[2][16][20];     // stride 80 B (16-aligned)
    __shared__ __align__(16) short h_s[2][16][72];     // stride 144 B (16-aligned)

    const int t    = threadIdx.x;
    const int lane = t & 63;
    const int w    = t >> 6;        // wave id 0..3
    const int quad = lane >> 4;     // 0..3
    const int l16  = lane & 15;

    // ---- setup (once per block) ----
    ((float4*)&w1_s[0][0])[t] = ((const float4*)W1)[t];          // 1024 floats

    const float cth = cosf(theta[t & 15]);
    const float4 b1v = ((const float4*)b1)[t >> 4];
    float b1a[4] = {b1v.x, b1v.y, b1v.z, b1v.w};

    // b2 per col-tile for the epilogue (col = l16 per validated C layout)
    float b2r[8];
#pragma unroll
    for (int tile = 0; tile < 8; ++tile)
        b2r[tile] = b2[w * 128 + tile * 16 + l16];

    // ---- W2 B-fragments (bf16, registers, whole block) ----
    short8 bfrag[8][2];
#pragma unroll
    for (int tile = 0; tile < 8; ++tile) {
        const int e = w * 128 + tile * 16 + l16;
#pragma unroll
        for (int s = 0; s < 2; ++s) {
            const int f0 = s * 32 + quad * 8;
            const float4* p = (const float4*)(W2 + (size_t)e * FFN + f0);
            float4 lo = p[0], hi = p[1];
            short8 bfr;
            bfr[0] = f2bf(lo.x); bfr[1] = f2bf(lo.y); bfr[2] = f2bf(lo.z); bfr[3] = f2bf(lo.w);
            bfr[4] = f2bf(hi.x); bfr[5] = f2bf(hi.y); bfr[6] = f2bf(hi.z); bfr[7] = f2bf(hi.w);
            bfrag[tile][s] = bfr;
        }
    }

    const int rowBase = blockIdx.x * ROWS_PER_BLOCK;

    for (int it = 0; it < MITERS; ++it) {
        const int buf  = it & 1;
        const int row0 = rowBase + it * 16;

        // ---- z phase: thread (zr=t>>4, zq=t&15); coalesced 64 B per row ----
        {
            const int zr = t >> 4, zq = t & 15;
            const float xv = x[(size_t)(row0 + zr) * EMBED + zq];
            z_s[buf][zr][zq] = cosf(xv) * cth;
        }
        __syncthreads();

        // ---- h phase: thread (r=t&15, g=t>>4) computes h[r][4g..4g+4) ----
        {
            const int r = t & 15, g = t >> 4;
            const float4 zr0 = *(const float4*)&z_s[buf][r][0];
            const float4 zr1 = *(const float4*)&z_s[buf][r][4];
            const float4 zr2 = *(const float4*)&z_s[buf][r][8];
            const float4 zr3 = *(const float4*)&z_s[buf][r][12];
            short4_t hv;
#pragma unroll
            for (int i = 0; i < 4; ++i) {
                const float4* wr = (const float4*)&w1_s[g * 4 + i][0];
                const float4 w0 = wr[0], w1r = wr[1], w2r = wr[2], w3r = wr[3];
                float s0 = b1a[i];
                s0 += zr0.x * w0.x  + zr0.y * w0.y  + zr0.z * w0.z  + zr0.w * w0.w;
                s0 += zr1.x * w1r.x + zr1.y * w1r.y + zr1.z * w1r.z + zr1.w * w1r.w;
                s0 += zr2.x * w2r.x + zr2.y * w2r.y + zr2.z * w2r.z + zr2.w * w2r.w;
                s0 += zr3.x * w3r.x + zr3.y * w3r.y + zr3.z * w3r.z + zr3.w * w3r.w;
                s0 = fmaxf(s0, 0.0f);                       // relu
                hv[i] = f2bf(s0);
            }
            *(short4_t*)&h_s[buf][r][g * 4] = hv;
        }
        __syncthreads();

        // ---- MFMA phase: A[m=l16][k=quad*8+j] from LDS, 8 col-tiles x 2 ksteps ----
        const short8 a0 = *(const short8*)&h_s[buf][l16][quad * 8];
        const short8 a1 = *(const short8*)&h_s[buf][l16][32 + quad * 8];

#pragma unroll
        for (int tile = 0; tile < 8; ++tile) {
            floatx4 acc = {0.f, 0.f, 0.f, 0.f};
            acc = __builtin_amdgcn_mfma_f32_16x16x32_bf16(a0, bfrag[tile][0], acc, 0, 0, 0);
            acc = __builtin_amdgcn_mfma_f32_16x16x32_bf16(a1, bfrag[tile][1], acc, 0, 0, 0);

            const int e = w * 128 + tile * 16 + l16;        // C col = lane&15
#pragma unroll
            for (int reg = 0; reg < 4; ++reg) {
                const int r = row0 + quad * 4 + reg;        // C row = quad*4 + reg
                out[(size_t)r * EMBED + e] = acc[reg] + b2r[tile];   // fp32 store
            }
        }
    }
}

extern "C" void kernel_launch(void* const* d_in, const int* in_sizes, int n_in,
                              void* d_out, int out_size, void* d_ws, size_t ws_size,
                              hipStream_t stream) {
    const float* x     = (const float*)d_in[0];
    const float* theta = (const float*)d_in[1];
    const float* W1    = (const float*)d_in[2];
    const float* b1    = (const float*)d_in[3];
    const float* W2    = (const float*)d_in[4];
    const float* b2    = (const float*)d_in[5];
    float* out = (float*)d_out;

    ffq_kernel<<<NBLOCKS, 256, 0, stream>>>(x, theta, W1, b1, W2, b2, out);
}